// Round 1
// 416.696 us; speedup vs baseline: 1.1491x; 1.1491x over previous
//
#include <hip/hip_runtime.h>

// SO3Linear: out[b,m,o] = sum_i x[b,m,i] * (W[l(m),o,i] - 1/sqrt(128)), bias on m=0.
// v2: operand-swapped MFMA (D[o][b] tile) -> each lane's 4 acc values are 4
// consecutive 'o' for one batch row => float4 nontemporal stores (8 per tile
// instead of 32 scalar dwords). x loads software-pipelined one tile ahead so
// converts wait on iteration-old loads (vmcnt<=16) and stores never serialize.
// Memory-bound: ~420 MB ideal HBM traffic -> ~67 us floor at 6.3 TB/s.

#define BATCH 16384
#define NUM_M 25
#define NF 128
#define BB 64                       // batch-chunks per m
#define ROWS_PER_BLOCK (BATCH / BB) // 256
#define TILE_ROWS 64                // 4 waves x 16 rows
#define NIT (ROWS_PER_BLOCK / TILE_ROWS) // 4

typedef __attribute__((ext_vector_type(8))) short short8;   // 8 bf16 (4 VGPRs)
typedef __attribute__((ext_vector_type(4))) float floatx4;  // MFMA C/D, float4 ld/st

// fp32 -> bf16, round-to-nearest-even (inputs finite; no NaN handling needed)
__device__ inline short f2bf(float f) {
    union { float f; unsigned u; } v;
    v.f = f;
    unsigned r = v.u + 0x7fffu + ((v.u >> 16) & 1u);
    return (short)(r >> 16);
}

__device__ inline short8 cvt8(floatx4 x0, floatx4 x1) {
    short8 f;
    f[0] = f2bf(x0[0]); f[1] = f2bf(x0[1]);
    f[2] = f2bf(x0[2]); f[3] = f2bf(x0[3]);
    f[4] = f2bf(x1[0]); f[5] = f2bf(x1[1]);
    f[6] = f2bf(x1[2]); f[7] = f2bf(x1[3]);
    return f;
}

__global__ __launch_bounds__(256, 2)
void so3_mfma_kernel(const float* __restrict__ x,
                     const float* __restrict__ w,
                     const float* __restrict__ bias,
                     float* __restrict__ out) {
    const int m = blockIdx.y;
    const int l = (m >= 16) ? 4 : (m >= 9) ? 3 : (m >= 4) ? 2 : (m >= 1) ? 1 : 0;
    const int wave = threadIdx.x >> 6;
    const int lane = threadIdx.x & 63;
    const int q    = lane >> 4;   // 0..3
    const int n16  = lane & 15;   // 0..15
    const float bound = 0.08838834764831843f; // 1/sqrt(128)

    // ---- W fragments (centered weights), registers for whole block ----
    // Used as MFMA *A*-operand: A[row=o][k=i]. Lane layout: row = lane&15,
    // k = q*8+j  ->  lane reads 8 contiguous i of weight row o = nt*16+n16.
    // (Identical lane data layout to the old B-operand usage — swap is free.)
    short8 wfrag[8][4];
    {
        const float* wl = w + l * NF * NF;
        #pragma unroll
        for (int nt = 0; nt < 8; ++nt) {
            const int o = nt * 16 + n16;
            #pragma unroll
            for (int kc = 0; kc < 4; ++kc) {
                const int k = kc * 32 + q * 8;
                const floatx4* p = (const floatx4*)(wl + o * NF + k);
                floatx4 w0 = p[0], w1 = p[1];
                short8 f;
                f[0] = f2bf(w0[0] - bound); f[1] = f2bf(w0[1] - bound);
                f[2] = f2bf(w0[2] - bound); f[3] = f2bf(w0[3] - bound);
                f[4] = f2bf(w1[0] - bound); f[5] = f2bf(w1[1] - bound);
                f[6] = f2bf(w1[2] - bound); f[7] = f2bf(w1[3] - bound);
                wfrag[nt][kc] = f;
            }
        }
    }

    const int b0 = blockIdx.x * ROWS_PER_BLOCK;
    // Per-lane row pointers: this lane owns batch row (b0 + wave*16 + n16) of
    // tile 0; subsequent tiles step by TILE_ROWS rows.
    const int row0 = b0 + wave * 16 + n16;
    const float* xr0  = x   + (row0 * NUM_M + m) * NF;
    float*       or0  = out + (row0 * NUM_M + m) * NF;
    const int tile_stride = TILE_ROWS * NUM_M * NF; // floats between tiles

    // ---- software pipeline: raw x data for tile it in raw[it&1] ----
    floatx4 raw[2][8];
    #pragma unroll
    for (int kc = 0; kc < 4; ++kc) {
        const floatx4* p = (const floatx4*)(xr0 + kc * 32 + q * 8);
        raw[0][2 * kc]     = p[0];
        raw[0][2 * kc + 1] = p[1];
    }

    #pragma unroll
    for (int it = 0; it < NIT; ++it) {
        const int cur = it & 1;   // compile-time after full unroll (no scratch)

        // prefetch next tile BEFORE any store of this tile: next iteration's
        // cvt waits only on these (older than the stores below in vmcnt order)
        if (it + 1 < NIT) {
            const float* xr = xr0 + (it + 1) * tile_stride;
            #pragma unroll
            for (int kc = 0; kc < 4; ++kc) {
                const floatx4* p = (const floatx4*)(xr + kc * 32 + q * 8);
                raw[cur ^ 1][2 * kc]     = p[0];
                raw[cur ^ 1][2 * kc + 1] = p[1];
            }
        }

        // ---- MFMA, kc-outer: produce/consume one a-fragment at a time ----
        floatx4 acc[8] = {};
        #pragma unroll
        for (int kc = 0; kc < 4; ++kc) {
            const short8 a = cvt8(raw[cur][2 * kc], raw[cur][2 * kc + 1]);
            #pragma unroll
            for (int nt = 0; nt < 8; ++nt) {
                // swapped operands: D[o][b], rows o = nt*16 + q*4 + r, col b = n16
                acc[nt] = __builtin_amdgcn_mfma_f32_16x16x32_bf16(
                    wfrag[nt][kc], a, acc[nt], 0, 0, 0);
            }
        }

        // ---- store: lane's 4 values are o = nt*16 + q*4 + (0..3), one row ----
        float* orow = or0 + it * tile_stride;
        #pragma unroll
        for (int nt = 0; nt < 8; ++nt) {
            floatx4 v = acc[nt];
            if (m == 0) {  // block-uniform branch; bias only on l=0 component
                const floatx4 b4 = *(const floatx4*)(bias + nt * 16 + q * 4);
                v[0] += b4[0]; v[1] += b4[1]; v[2] += b4[2]; v[3] += b4[3];
            }
            __builtin_nontemporal_store(v, (floatx4*)(orow + nt * 16 + q * 4));
        }
    }
}

extern "C" void kernel_launch(void* const* d_in, const int* in_sizes, int n_in,
                              void* d_out, int out_size, void* d_ws, size_t ws_size,
                              hipStream_t stream) {
    const float* x    = (const float*)d_in[0]; // [16384, 25, 128]
    const float* w    = (const float*)d_in[1]; // [5, 128, 128]
    const float* bias = (const float*)d_in[2]; // [128]
    float* out = (float*)d_out;                // [16384, 25, 128]

    dim3 grid(BB, NUM_M);
    dim3 block(256);
    so3_mfma_kernel<<<grid, block, 0, stream>>>(x, w, bias, out);
}

// Round 2
// 396.148 us; speedup vs baseline: 1.2087x; 1.0519x over previous
//
#include <hip/hip_runtime.h>

// SO3Linear: out[b,m,o] = sum_i x[b,m,i] * (W[l(m),o,i] - 1/sqrt(128)), bias on m=0.
// v3: W kept in LDS as pre-converted bf16 (32 KB, XOR-swizzled), loaded ONCE per
// block. v2's wfrag[8][4] needed 128 VGPRs but VGPR_Count was 116 -> compiler was
// rematerializing W (L2 reload + reconvert) EVERY tile iteration; that was the
// ~15k-cycle stall per iteration. With W in LDS, true reg pressure ~120 ->
// __launch_bounds__(256,4) doubles occupancy to 4 blocks/CU (16 waves).
// Memory-bound: ~420 MB ideal HBM traffic -> ~67 us floor at 6.3 TB/s.

#define BATCH 16384
#define NUM_M 25
#define NF 128
#define BB 64                       // batch-chunks per m
#define ROWS_PER_BLOCK (BATCH / BB) // 256
#define TILE_ROWS 64                // 4 waves x 16 rows
#define NIT (ROWS_PER_BLOCK / TILE_ROWS) // 4

typedef __attribute__((ext_vector_type(8))) short short8;   // 8 bf16 (4 VGPRs)
typedef __attribute__((ext_vector_type(4))) float floatx4;  // MFMA C/D, float4 ld/st

// fp32 -> bf16, round-to-nearest-even (inputs finite; no NaN handling needed)
__device__ inline short f2bf(float f) {
    union { float f; unsigned u; } v;
    v.f = f;
    unsigned r = v.u + 0x7fffu + ((v.u >> 16) & 1u);
    return (short)(r >> 16);
}

__device__ inline short8 cvt8(floatx4 x0, floatx4 x1) {
    short8 f;
    f[0] = f2bf(x0[0]); f[1] = f2bf(x0[1]);
    f[2] = f2bf(x0[2]); f[3] = f2bf(x0[3]);
    f[4] = f2bf(x1[0]); f[5] = f2bf(x1[1]);
    f[6] = f2bf(x1[2]); f[7] = f2bf(x1[3]);
    return f;
}

__global__ __launch_bounds__(256, 4)
void so3_mfma_kernel(const float* __restrict__ x,
                     const float* __restrict__ w,
                     const float* __restrict__ bias,
                     float* __restrict__ out) {
    // W[l] as bf16, row o at byte o*256, 16B chunk c at (c*16)^((o&7)<<4).
    // Swizzle spreads the fragment ds_read_b128s across all 32 banks
    // (unswizzled: lanes with equal q share one 4-bank group -> 2x penalty).
    __shared__ short wlds[NF * NF];   // 32 KB

    const int m = blockIdx.y;
    const int l = (m >= 16) ? 4 : (m >= 9) ? 3 : (m >= 4) ? 2 : (m >= 1) ? 1 : 0;
    const int tid  = threadIdx.x;
    const int wave = tid >> 6;
    const int lane = tid & 63;
    const int q    = lane >> 4;   // 0..3
    const int n16  = lane & 15;   // 0..15
    const float bound = 0.08838834764831843f; // 1/sqrt(128)

    const int b0   = blockIdx.x * ROWS_PER_BLOCK;
    const int row0 = b0 + wave * 16 + n16;     // this lane's tile-0 batch row
    const float* xr0 = x   + (row0 * NUM_M + m) * NF;
    float*       or0 = out + (row0 * NUM_M + m) * NF;
    const int tile_stride = TILE_ROWS * NUM_M * NF; // floats between tiles

    // ---- issue x tile-0 loads FIRST: in flight during the whole W prologue ----
    floatx4 raw[8];
    #pragma unroll
    for (int kc = 0; kc < 4; ++kc) {
        const floatx4* p = (const floatx4*)(xr0 + kc * 32 + q * 8);
        raw[2 * kc]     = p[0];
        raw[2 * kc + 1] = p[1];
    }

    // ---- prologue: W[l] (fp32, global) -> centered bf16 -> swizzled LDS ----
    // thread t: row o = t>>1, 64 floats starting at col (t&1)*64.
    {
        const int o    = tid >> 1;
        const int half = tid & 1;
        const float* wr = w + l * NF * NF + o * NF + half * 64;
        char* wb = (char*)wlds;
        #pragma unroll
        for (int j = 0; j < 8; ++j) {          // 8 chunks of 8 floats -> short8
            floatx4 f0 = ((const floatx4*)wr)[2 * j];
            floatx4 f1 = ((const floatx4*)wr)[2 * j + 1];
            short8 s;
            s[0] = f2bf(f0[0] - bound); s[1] = f2bf(f0[1] - bound);
            s[2] = f2bf(f0[2] - bound); s[3] = f2bf(f0[3] - bound);
            s[4] = f2bf(f1[0] - bound); s[5] = f2bf(f1[1] - bound);
            s[6] = f2bf(f1[2] - bound); s[7] = f2bf(f1[3] - bound);
            const int c = half * 8 + j;
            *(short8*)(wb + o * 256 + ((c * 16) ^ ((o & 7) << 4))) = s;
        }
    }
    __syncthreads();

    // ---- per-lane swizzled LDS read addresses (computed once) ----
    // fragment (nt,kc): row o = nt*16+n16, bytes (kc*64+q*16)^((n16&7)<<4);
    // nt*4096 folds into the ds_read offset immediate.
    const char* wb = (const char*)wlds;
    const int xm = (n16 & 7) << 4;
    int lr[4];
    #pragma unroll
    for (int kc = 0; kc < 4; ++kc)
        lr[kc] = n16 * 256 + ((kc * 64 + q * 16) ^ xm);

    // tile-0 A fragments (loads issued long ago; cvt waits only here)
    short8 afrag[4];
    #pragma unroll
    for (int kc = 0; kc < 4; ++kc)
        afrag[kc] = cvt8(raw[2 * kc], raw[2 * kc + 1]);

    #pragma unroll
    for (int it = 0; it < NIT; ++it) {
        // prefetch next tile (oldest vmem this iteration: cvt below waits
        // vmcnt(8) with only this iteration's stores younger)
        if (it + 1 < NIT) {
            const float* xr = xr0 + (it + 1) * tile_stride;
            #pragma unroll
            for (int kc = 0; kc < 4; ++kc) {
                const floatx4* p = (const floatx4*)(xr + kc * 32 + q * 8);
                raw[2 * kc]     = p[0];
                raw[2 * kc + 1] = p[1];
            }
        }

        // ---- MFMA: W fragments streamed from LDS, swapped operands D[o][b] ----
        floatx4 acc[8] = {};
        #pragma unroll
        for (int kc = 0; kc < 4; ++kc) {
            short8 wt[8];
            #pragma unroll
            for (int nt = 0; nt < 8; ++nt)
                wt[nt] = *(const short8*)(wb + lr[kc] + nt * 4096);
            #pragma unroll
            for (int nt = 0; nt < 8; ++nt)
                acc[nt] = __builtin_amdgcn_mfma_f32_16x16x32_bf16(
                    wt[nt], afrag[kc], acc[nt], 0, 0, 0);
        }

        // ---- store: lane's 4 values are o = nt*16 + q*4 + (0..3), one row ----
        float* orow = or0 + it * tile_stride;
        #pragma unroll
        for (int nt = 0; nt < 8; ++nt) {
            floatx4 v = acc[nt];
            if (m == 0) {  // block-uniform; bias only on l=0 component
                const floatx4 b4 = *(const floatx4*)(bias + nt * 16 + q * 4);
                v[0] += b4[0]; v[1] += b4[1]; v[2] += b4[2]; v[3] += b4[3];
            }
            __builtin_nontemporal_store(v, (floatx4*)(orow + nt * 16 + q * 4));
        }

        // ---- convert prefetched tile for next iteration ----
        if (it + 1 < NIT) {
            #pragma unroll
            for (int kc = 0; kc < 4; ++kc)
                afrag[kc] = cvt8(raw[2 * kc], raw[2 * kc + 1]);
        }
    }
}

extern "C" void kernel_launch(void* const* d_in, const int* in_sizes, int n_in,
                              void* d_out, int out_size, void* d_ws, size_t ws_size,
                              hipStream_t stream) {
    const float* x    = (const float*)d_in[0]; // [16384, 25, 128]
    const float* w    = (const float*)d_in[1]; // [5, 128, 128]
    const float* bias = (const float*)d_in[2]; // [128]
    float* out = (float*)d_out;                // [16384, 25, 128]

    dim3 grid(BB, NUM_M);
    dim3 block(256);
    so3_mfma_kernel<<<grid, block, 0, stream>>>(x, w, bias, out);
}

// Round 3
// 373.050 us; speedup vs baseline: 1.2836x; 1.0619x over previous
//
#include <hip/hip_runtime.h>

// SO3Linear: out[b,m,o] = sum_i x[b,m,i] * (W[l(m),o,i] - 1/sqrt(128)), bias on m=0.
// v4: fully-coalesced global traffic. v0-v3 all plateaued at 2.0-2.4 TB/s because
// every global load/store instruction touched 16-64 scattered 64B lines at 12.8KB
// stride (one 16B chunk per batch-row per lane) -- a DRAM page-locality killer.
// Now: x is loaded half-wave-per-row (512B contiguous bursts), converted to bf16,
// staged in swizzled LDS; MFMA fragments come from ds_read_b128. Output goes
// acc -> swizzled LDS -> row-contiguous readback -> 512B-per-row nontemporal
// stores. Prefetch of tile it+1 is pinned early with sched_barrier(0) (v2/v3's
// pipeline was silently collapsed by the compiler -- VGPR_Count=48 proved it).
// LDS: W 32K + x 16K + out 32K = 80KB -> 2 blocks/CU.
// Memory-bound: ~420 MB ideal HBM traffic -> ~67 us floor at 6.3 TB/s.

#define BATCH 16384
#define NUM_M 25
#define NF 128
#define BB 64                       // batch-chunks per m
#define ROWS_PER_BLOCK (BATCH / BB) // 256
#define TILE_ROWS 64                // rows staged per iteration
#define NIT (ROWS_PER_BLOCK / TILE_ROWS) // 4

typedef __attribute__((ext_vector_type(8))) short short8;   // 8 bf16 (4 VGPRs)
typedef __attribute__((ext_vector_type(4))) short bf16x4;   // 4 bf16 (8 B)
typedef __attribute__((ext_vector_type(4))) float floatx4;  // MFMA C/D, 16 B ld/st

// fp32 -> bf16, round-to-nearest-even (inputs finite; no NaN handling needed)
__device__ inline short f2bf(float f) {
    union { float f; unsigned u; } v;
    v.f = f;
    unsigned r = v.u + 0x7fffu + ((v.u >> 16) & 1u);
    return (short)(r >> 16);
}

__global__ __launch_bounds__(256, 2)
void so3_mfma_kernel(const float* __restrict__ x,
                     const float* __restrict__ w,
                     const float* __restrict__ bias,
                     float* __restrict__ out) {
    // All three tiles XOR-swizzled: logical byte c of row r lives at
    // c ^ ((r&7)<<4). Balances every b128 access at the 8-lanes-per-
    // bank-group minimum; bijective per row (XOR touches bits 4..6 only).
    __shared__ short wlds[NF * NF];         // 32 KB: W[l] bf16, row o = 256 B
    __shared__ short xlds[TILE_ROWS * NF];  // 16 KB: x tile bf16, row = 256 B
    __shared__ float olds[TILE_ROWS * NF];  // 32 KB: out tile fp32, row = 512 B

    const int m = blockIdx.y;
    const int l = (m >= 16) ? 4 : (m >= 9) ? 3 : (m >= 4) ? 2 : (m >= 1) ? 1 : 0;
    const int tid  = threadIdx.x;
    const int lane = tid & 63;
    const int wave = tid >> 6;
    const int q    = lane >> 4;   // 0..3
    const int n16  = lane & 15;   // 0..15
    const int hw   = tid >> 5;    // half-wave 0..7 (row-parallel staging)
    const int j    = tid & 31;    // lane-in-half-wave (column within a row)
    const float bound = 0.08838834764831843f; // 1/sqrt(128)
    const int b0 = blockIdx.x * ROWS_PER_BLOCK;

    // ---- tile-0 x loads FIRST (fly during whole W prologue) ----
    // Coalesced: half-wave = one 512B row; per instr = 2 contiguous 512B bursts.
    floatx4 raw[8];
    #pragma unroll
    for (int k = 0; k < 8; ++k) {
        const int r = b0 + hw * 8 + k;
        raw[k] = *(const floatx4*)(x + (r * NUM_M + m) * NF + j * 4);
    }
    __builtin_amdgcn_sched_barrier(0);  // do not sink these loads

    // ---- W[l] fp32 -> centered bf16 -> swizzled LDS (once per block) ----
    {
        const int o    = tid >> 1;
        const int half = tid & 1;
        const float* wr = w + l * NF * NF + o * NF + half * 64;
        char* wbp = (char*)wlds;
        #pragma unroll
        for (int jj = 0; jj < 8; ++jj) {
            floatx4 f0 = ((const floatx4*)wr)[2 * jj];
            floatx4 f1 = ((const floatx4*)wr)[2 * jj + 1];
            short8 s;
            s[0] = f2bf(f0[0] - bound); s[1] = f2bf(f0[1] - bound);
            s[2] = f2bf(f0[2] - bound); s[3] = f2bf(f0[3] - bound);
            s[4] = f2bf(f1[0] - bound); s[5] = f2bf(f1[1] - bound);
            s[6] = f2bf(f1[2] - bound); s[7] = f2bf(f1[3] - bound);
            const int c = half * 8 + jj;
            *(short8*)(wbp + o * 256 + ((c * 16) ^ ((o & 7) << 4))) = s;
        }
    }
    // ---- stage tile 0: cvt + swizzled LDS write (row r&7 == k) ----
    {
        char* xbp = (char*)xlds;
        #pragma unroll
        for (int k = 0; k < 8; ++k) {
            bf16x4 s;
            s[0] = f2bf(raw[k][0]); s[1] = f2bf(raw[k][1]);
            s[2] = f2bf(raw[k][2]); s[3] = f2bf(raw[k][3]);
            const int r = hw * 8 + k;
            *(bf16x4*)(xbp + r * 256 + ((j * 8) ^ (k << 4))) = s;
        }
    }
    __syncthreads();

    // ---- per-lane fragment offsets (W row o=nt*16+n16; x row wave*16+n16;
    //      both have row&7 == n16&7, so one swizzle key serves both) ----
    const char* wbp = (const char*)wlds;
    const char* xbp = (const char*)xlds;
    char* obp = (char*)olds;
    const int xm = (n16 & 7) << 4;
    int lr[4];
    #pragma unroll
    for (int kc = 0; kc < 4; ++kc)
        lr[kc] = n16 * 256 + ((kc * 64 + q * 16) ^ xm);

    floatx4 bval = {0.0f, 0.0f, 0.0f, 0.0f};
    if (m == 0) bval = *(const floatx4*)(bias + j * 4);  // bias only on l=0

    for (int it = 0; it < NIT; ++it) {
        // prefetch next tile (coalesced); pin above compute so the loads get
        // the full MFMA + barrier phase to land
        if (it + 1 < NIT) {
            #pragma unroll
            for (int k = 0; k < 8; ++k) {
                const int r = b0 + (it + 1) * TILE_ROWS + hw * 8 + k;
                raw[k] = *(const floatx4*)(x + (r * NUM_M + m) * NF + j * 4);
            }
            __builtin_amdgcn_sched_barrier(0);
        }

        // ---- MFMA from LDS (swapped operands: D[o][b]) ----
        floatx4 acc[8] = {};
        #pragma unroll
        for (int kc = 0; kc < 4; ++kc) {
            const short8 a = *(const short8*)(xbp + wave * 4096 + lr[kc]);
            short8 wt[8];
            #pragma unroll
            for (int nt = 0; nt < 8; ++nt)
                wt[nt] = *(const short8*)(wbp + lr[kc] + nt * 4096);
            #pragma unroll
            for (int nt = 0; nt < 8; ++nt)
                acc[nt] = __builtin_amdgcn_mfma_f32_16x16x32_bf16(
                    wt[nt], a, acc[nt], 0, 0, 0);
        }

        // ---- acc -> swizzled out tile (lane's frag nt = cols nt*16+q*4..+3
        //      of batch row wave*16+n16) ----
        const int orow = (wave * 16 + n16) * 512;
        #pragma unroll
        for (int nt = 0; nt < 8; ++nt)
            *(floatx4*)(obp + orow + ((nt * 64 + q * 16) ^ xm)) = acc[nt];

        __syncthreads();  // acc tile complete; xlds reads of this tile done

        // ---- stage next x tile (cvt of prefetched regs; vmcnt wait is here,
        //      a full compute phase after issue) ----
        if (it + 1 < NIT) {
            #pragma unroll
            for (int k = 0; k < 8; ++k) {
                bf16x4 s;
                s[0] = f2bf(raw[k][0]); s[1] = f2bf(raw[k][1]);
                s[2] = f2bf(raw[k][2]); s[3] = f2bf(raw[k][3]);
                const int r = hw * 8 + k;
                *(bf16x4*)((char*)xlds + r * 256 + ((j * 8) ^ (k << 4))) = s;
            }
        }

        // ---- readback + coalesced store: half-wave = one 512B out row ----
        #pragma unroll
        for (int k = 0; k < 8; ++k) {
            const int rloc = hw * 8 + k;   // rloc&7 == k -> uniform swizzle key
            floatx4 v = *(const floatx4*)(obp + rloc * 512 + ((j * 16) ^ (k << 4)));
            v[0] += bval[0]; v[1] += bval[1]; v[2] += bval[2]; v[3] += bval[3];
            const int r = b0 + it * TILE_ROWS + rloc;
            __builtin_nontemporal_store(
                v, (floatx4*)(out + (r * NUM_M + m) * NF + j * 4));
        }

        __syncthreads();  // xlds staged & olds readback done before next iter
    }
}

extern "C" void kernel_launch(void* const* d_in, const int* in_sizes, int n_in,
                              void* d_out, int out_size, void* d_ws, size_t ws_size,
                              hipStream_t stream) {
    const float* x    = (const float*)d_in[0]; // [16384, 25, 128]
    const float* w    = (const float*)d_in[1]; // [5, 128, 128]
    const float* bias = (const float*)d_in[2]; // [128]
    float* out = (float*)d_out;                // [16384, 25, 128]

    dim3 grid(BB, NUM_M);
    dim3 block(256);
    so3_mfma_kernel<<<grid, block, 0, stream>>>(x, w, bias, out);
}